// Round 4
// baseline (986.880 us; speedup 1.0000x reference)
//
#include <hip/hip_runtime.h>
#include <math.h>

#define D_MODEL 1024
#define HIDDEN  4096
#define NEXP    8
#define NVEXP   10   // 8 routed + 2 shared

typedef __attribute__((ext_vector_type(8))) short short8;
typedef __attribute__((ext_vector_type(4))) float floatx4;

__device__ __forceinline__ unsigned short f2bf(float f) {
    unsigned int u = __float_as_uint(f);
    unsigned int r = (u + 0x7fffu + ((u >> 16) & 1u)) >> 16;
    return (unsigned short)r;
}

__device__ __forceinline__ void gll16(const void* g, void* l) {
    __builtin_amdgcn_global_load_lds(
        (const __attribute__((address_space(1))) unsigned int*)g,
        (__attribute__((address_space(3))) unsigned int*)l, 16, 0, 0);
}

__device__ __forceinline__ void barfence() {
    __builtin_amdgcn_s_barrier();
    asm volatile("" ::: "memory");   // keep later LDS ops from hoisting above
}

// ---------------- router: wave per token, fp32 gates -------------------
__global__ __launch_bounds__(256) void router_kernel(
        const float* __restrict__ x, const float* __restrict__ rW,
        const float* __restrict__ rb, int* __restrict__ te, float* __restrict__ tw,
        int* __restrict__ cnt) {
    __shared__ float rws[8 * 1024];   // rws[e][d]
    int tid = threadIdx.x;
    for (int i = tid; i < 8192; i += 256) {
        int dd = i >> 3, e = i & 7;
        rws[e * 1024 + dd] = rW[i];
    }
    __syncthreads();
    int tok = blockIdx.x * 4 + (tid >> 6);
    int lane = tid & 63;
    const float* xr = x + (size_t)tok * D_MODEL;
    float acc[8];
#pragma unroll
    for (int e = 0; e < 8; ++e) acc[e] = 0.f;
    for (int k = 0; k < 16; ++k) {
        int dd = k * 64 + lane;
        float xv = xr[dd];
#pragma unroll
        for (int e = 0; e < 8; ++e) acc[e] += xv * rws[e * 1024 + dd];
    }
#pragma unroll
    for (int m = 1; m < 64; m <<= 1) {
#pragma unroll
        for (int e = 0; e < 8; ++e) acc[e] += __shfl_xor(acc[e], m);
    }
    if (lane == 0) {
        float g[8];
#pragma unroll
        for (int e = 0; e < 8; ++e) g[e] = acc[e] + rb[e];
        int i0 = 0; float v0 = g[0];
#pragma unroll
        for (int e = 1; e < 8; ++e) if (g[e] > v0) { v0 = g[e]; i0 = e; }
        int i1 = -1; float v1 = -1e30f;
#pragma unroll
        for (int e = 0; e < 8; ++e) if (e != i0 && g[e] > v1) { v1 = g[e]; i1 = e; }
        float ex = expf(v1 - v0);
        float p0 = 1.0f / (1.0f + ex);
        float p1 = 1.0f - p0;
        te[tok * 2] = i0; te[tok * 2 + 1] = i1;
        tw[tok * 2] = p0; tw[tok * 2 + 1] = p1;
        atomicAdd(cnt + i0, 1);
        atomicAdd(cnt + i1, 1);
    }
}

// offs[e] padded to multiples of 256 (BM=256); offs[8] = shared-A base,
// offs[9] = z=9 out base. tmap: [0]=ntiles, [1+i] = z | (mtile<<8) for each
// active 256-row tile (dense, ordered) -> compacted gemm grid.
__global__ void scan_kernel(const int* __restrict__ cnt, int* __restrict__ offs,
                            int* __restrict__ cnt2, int* __restrict__ tmap) {
    if (threadIdx.x == 0) {
        int o = 0;
        for (int e = 0; e < 8; ++e) { offs[e] = o; o += (cnt[e] + 255) & ~255; }
        offs[8] = o; offs[9] = o + 4096;
        int nt = 0;
        for (int e = 0; e < NVEXP; ++e) {
            int c = (e < 8) ? cnt[e] : 4096;
            for (int m = 0; m * 256 < c; ++m) tmap[1 + nt++] = e | (m << 8);
        }
        tmap[0] = nt;   // <= 71
    }
    if (threadIdx.x < 8) cnt2[threadIdx.x] = 0;
}

__global__ __launch_bounds__(256) void scatter_kernel(
        const int* __restrict__ te, const float* __restrict__ tw,
        const int* __restrict__ offs, int* __restrict__ cnt2,
        int* __restrict__ ptok, float* __restrict__ pw, int* __restrict__ tpair) {
    int t = blockIdx.x * 256 + threadIdx.x;
    int e0 = te[2 * t], e1 = te[2 * t + 1];
    int s0 = atomicAdd(cnt2 + e0, 1);
    int pos0 = offs[e0] + s0;
    ptok[pos0] = t; pw[pos0] = tw[2 * t];
    int s1 = atomicAdd(cnt2 + e1, 1);
    int pos1 = offs[e1] + s1;
    ptok[pos1] = t; pw[pos1] = tw[2 * t + 1];
    int b8 = offs[8], b9 = offs[9];
    ptok[b8 + t] = t; pw[b8 + t] = 0.5f;
    ptok[b9 + t] = t; pw[b9 + t] = 0.5f;
    tpair[4 * t + 0] = pos0; tpair[4 * t + 1] = pos1;
    tpair[4 * t + 2] = b8 + t; tpair[4 * t + 3] = b9 + t;
}

// ------- weight pack (both groups, one launch) -------------------------
// src fp32 [R(k)][C(n)] -> [z][ntile(C/256)][kc(R/64)][frag16][kstep2][lane64][8]
__global__ __launch_bounds__(256) void wpack_all(
        const float* __restrict__ W1, const float* __restrict__ sW1,
        const float* __restrict__ W2, const float* __restrict__ sW2,
        unsigned short* __restrict__ Wp1, unsigned short* __restrict__ Wp2) {
    int bid = blockIdx.x;
    const float* src; unsigned short* dst;
    int R, C, cx, ry, z;
    if (bid < 10240) {            // group 1: R=1024, C=4096 (64 c-tiles, 16 r-tiles)
        z = bid >> 10; int rem = bid & 1023;
        cx = rem & 63; ry = rem >> 6;
        R = 1024; C = 4096;
        src = (z < NEXP) ? W1 + (size_t)z * R * C : sW1 + (size_t)(z - NEXP) * R * C;
        dst = Wp1;
    } else {                      // group 2: R=4096, C=1024 (16 c-tiles, 64 r-tiles)
        bid -= 10240;
        z = bid >> 10; int rem = bid & 1023;
        cx = rem & 15; ry = rem >> 4;
        R = 4096; C = 1024;
        src = (z < NEXP) ? W2 + (size_t)z * R * C : sW2 + (size_t)(z - NEXP) * R * C;
        dst = Wp2;
    }
    int c0 = cx * 64, r0 = ry * 64;
    __shared__ float tile[64][65];
    int t = threadIdx.x;
    int rl = t >> 4, cl = (t & 15) * 4;
#pragma unroll
    for (int p = 0; p < 4; ++p) {
        int r = p * 16 + rl;
        const float4 v = *(const float4*)&src[(size_t)(r0 + r) * C + c0 + cl];
        tile[r][cl] = v.x; tile[r][cl + 1] = v.y; tile[r][cl + 2] = v.z; tile[r][cl + 3] = v.w;
    }
    __syncthreads();
    int NT = C >> 8, NKC = R >> 6;
    int ntile = c0 >> 8, f0 = (c0 >> 4) & 15, kc = ry;
    unsigned short* base = dst + ((size_t)(z * NT + ntile) * NKC + kc) * 16384;
#pragma unroll
    for (int w = 0; w < 2; ++w) {
        int si = w * 256 + t;            // 0..511
        int fl = si >> 7, rem = si & 127;
        int kst = rem >> 6, l2 = rem & 63;
        int n_l = fl * 16 + (l2 & 15);
        int k_l = kst * 32 + (l2 >> 4) * 8;
        unsigned int u[4];
#pragma unroll
        for (int i = 0; i < 4; ++i) {
            unsigned short lo = f2bf(tile[k_l + 2 * i][n_l]);
            unsigned short hi = f2bf(tile[k_l + 2 * i + 1][n_l]);
            u[i] = lo | ((unsigned)hi << 16);
        }
        *(uint4*)(base + ((size_t)(f0 + fl) * 2 + kst) * 512 + (size_t)l2 * 8) =
            make_uint4(u[0], u[1], u[2], u[3]);
    }
}

// ------- A pack (phase 1): gather x rows by ptok, cast, fragment-pack --
// dst layout: [gm128][kc16][frag8][kstep2][lane64][8]  (16KB pages)
__global__ __launch_bounds__(256) void apack_kernel(
        const float* __restrict__ x, const int* __restrict__ counts,
        const int* __restrict__ offs, const int* __restrict__ ptok,
        unsigned short* __restrict__ dst) {
    int z = blockIdx.z;               // 0..8 (8 = shared section, written once)
    int cnt = (z < NEXP) ? counts[z] : 4096;
    int cntp = (z < NEXP) ? ((cnt + 255) & ~255) : 4096;  // fill up to 256-pad
    int pbase = offs[z];
    int mtile = blockIdx.y;
    if (mtile * 128 >= cntp) return;
    int kc = blockIdx.x;
    int gm = (pbase >> 7) + mtile;
    unsigned short* d = dst + ((size_t)gm * 16 + kc) * 8192;
    int t = threadIdx.x;
#pragma unroll
    for (int w = 0; w < 4; ++w) {
        int si = w * 256 + t;            // 0..1023
        int fl = si >> 7, rem = si & 127;
        int kst = rem >> 6, l2 = rem & 63;
        int row = fl * 16 + (l2 & 15);
        int k0 = kc * 64 + kst * 32 + (l2 >> 4) * 8;
        int idx = mtile * 128 + row;
        if (idx >= cnt) idx = cnt - 1;
        int tok = ptok[pbase + idx];
        const float4* p = (const float4*)(x + (size_t)tok * D_MODEL + k0);
        float4 a = p[0], b = p[1];
        unsigned int u0 = f2bf(a.x) | ((unsigned)f2bf(a.y) << 16);
        unsigned int u1 = f2bf(a.z) | ((unsigned)f2bf(a.w) << 16);
        unsigned int u2 = f2bf(b.x) | ((unsigned)f2bf(b.y) << 16);
        unsigned int u3 = f2bf(b.z) | ((unsigned)f2bf(b.w) << 16);
        *(uint4*)(d + (size_t)si * 8) = make_uint4(u0, u1, u2, u3);
    }
}

// -------- grouped MFMA GEMM: BM=256, BN=256, BK=64, 8 waves (2M x 4N) ---
// COMPACTED grid: x = dense tile slot (<=72), y = ntile; (z,mtile) from tmap.
// Eliminates the periodic early-exit pattern that serialized routed experts
// onto 1/4 of the CUs. XCD-chunked bijective swizzle (72*NT % 8 == 0).
// Deep-lookahead double buffer: during iter k (reading buf d=k&1), restage
// tile k+2 into buf d slot-by-slot as each slot's fragments move to regs;
// certify tile k+1 with vmcnt(8) (its loads were issued during iter k-1).
template <int NKC, int NT, int PHASE>
__global__ __launch_bounds__(512, 2) void moe_gemm(
        const unsigned short* __restrict__ Wp,
        const unsigned short* __restrict__ Ap,
        const float* __restrict__ bias, const float* __restrict__ sbias,
        const int* __restrict__ tmap, const int* __restrict__ offs,
        unsigned short* __restrict__ Aout, float* __restrict__ buf) {
    extern __shared__ __align__(16) short smem[];

    const unsigned nwg = 72u * (unsigned)NT;
    const unsigned wid = blockIdx.x + 72u * blockIdx.y;
    const unsigned w = (wid & 7u) * (nwg >> 3) + (wid >> 3);
    const int tile = (int)(w % 72u);
    const int ntile = (int)(w / 72u);
    if (tile >= tmap[0]) return;
    const int tv = tmap[1 + tile];
    const int z = tv & 255;
    const int mtile = tv >> 8;

    const int outbase = offs[z];
    const int inbase = (PHASE == 1 && z >= NEXP) ? offs[8] : outbase;
    const int tid = threadIdx.x;
    const int wave = tid >> 6, lane = tid & 63;
    const int wm = wave >> 2, wn = wave & 3;   // 2 x 4
    const int gm0 = (inbase >> 7) + 2 * mtile;
    const int NDIM = NT * 256;

    const unsigned short* Bpg = Wp + (size_t)(z * NT + ntile) * NKC * 16384;
    const float* be = (z < NEXP) ? bias + (size_t)z * NDIM
                                 : sbias + (size_t)(z - NEXP) * NDIM;

    // slots: 0=A0, 1=A1, 2=B0, 3=B1; each 8192 shorts (16KB)
    auto stageA = [&](int kt, int mh, int d) {
        const unsigned short* g = Ap + ((size_t)(gm0 + mh) * NKC + kt) * 8192 + tid * 8;
        short* l = smem + (d * 4 + mh) * 8192 + tid * 8;
        gll16(g, l); gll16(g + 4096, l + 4096);
    };
    auto stageB = [&](int kt, int nh, int d) {
        const unsigned short* g = Bpg + (size_t)kt * 16384 + nh * 8192 + tid * 8;
        short* l = smem + (d * 4 + 2 + nh) * 8192 + tid * 8;
        gll16(g, l); gll16(g + 4096, l + 4096);
    };

    short8 af0[4][2], af1[4][2], bf0[2][2], bf1[2][2];
    auto readA = [&](short8 (*af)[2], int mh, int d) {
        const short* base = smem + (d * 4 + mh) * 8192 + lane * 8;
#pragma unroll
        for (int s = 0; s < 4; ++s)
#pragma unroll
            for (int ks = 0; ks < 2; ++ks)
                af[s][ks] = *(const short8*)(base + ((wm * 4 + s) * 2 + ks) * 512);
    };
    auto readB = [&](short8 (*bf)[2], int nh, int d) {
        const short* base = smem + (d * 4 + 2 + nh) * 8192 + lane * 8;
#pragma unroll
        for (int r = 0; r < 2; ++r)
#pragma unroll
            for (int ks = 0; ks < 2; ++ks)
                bf[r][ks] = *(const short8*)(base + ((wn * 2 + r) * 2 + ks) * 512);
    };

    floatx4 acc[2][4][2][2];
#pragma unroll
    for (int mh = 0; mh < 2; ++mh)
#pragma unroll
        for (int s = 0; s < 4; ++s)
#pragma unroll
            for (int nh = 0; nh < 2; ++nh)
#pragma unroll
                for (int r = 0; r < 2; ++r)
                    acc[mh][s][nh][r] = (floatx4){0.f, 0.f, 0.f, 0.f};

    auto mmac = [&](int mh, short8 (*af)[2], int nh, short8 (*bf)[2]) {
        __builtin_amdgcn_s_setprio(1);
#pragma unroll
        for (int s = 0; s < 4; ++s)
#pragma unroll
            for (int r = 0; r < 2; ++r)
#pragma unroll
                for (int ks = 0; ks < 2; ++ks)
                    acc[mh][s][nh][r] = __builtin_amdgcn_mfma_f32_16x16x32_bf16(
                        af[s][ks], bf[r][ks], acc[mh][s][nh][r], 0, 0, 0);
        __builtin_amdgcn_s_setprio(0);
    };

    // ---- prologue: stage tiles 0 and 1 fully; certify tile 0 ----
    stageA(0, 0, 0); stageB(0, 0, 0); stageA(0, 1, 0); stageB(0, 1, 0);
    asm volatile("" ::: "memory");       // keep tile-0 stages oldest in queue
    stageA(1, 0, 1); stageB(1, 0, 1); stageA(1, 1, 1); stageB(1, 1, 1);
    asm volatile("s_waitcnt vmcnt(8)" ::: "memory");
    barfence();

    for (int k = 0; k < NKC; ++k) {
        const int d = k & 1;
        // ---- P0: read A0,B0; mfma m0 x n0 ----
        readA(af0, 0, d); readB(bf0, 0, d);
        barfence();
        asm volatile("s_waitcnt lgkmcnt(0)" ::: "memory");
        mmac(0, af0, 0, bf0);
        barfence();
        // ---- P1: read A1; stage A0,B0(k+2)->d; mfma m1 x n0 ----
        readA(af1, 1, d);
        if (k + 2 < NKC) { stageA(k + 2, 0, d); stageB(k + 2, 0, d); }
        barfence();
        asm volatile("s_waitcnt lgkmcnt(0)" ::: "memory");
        mmac(1, af1, 0, bf0);
        barfence();
        // ---- P2: read B1; stage A1(k+2)->d; mfma m1 x n1 ----
        readB(bf1, 1, d);
        if (k + 2 < NKC) stageA(k + 2, 1, d);
        barfence();
        asm volatile("s_waitcnt lgkmcnt(0)" ::: "memory");
        mmac(1, af1, 1, bf1);
        barfence();
        // ---- P3: stage B1(k+2)->d; certify tile k+1; mfma m0 x n1 ----
        if (k + 2 < NKC) {
            stageB(k + 2, 1, d);
            asm volatile("s_waitcnt vmcnt(8)" ::: "memory");
        } else if (k + 1 < NKC) {
            asm volatile("s_waitcnt vmcnt(0)" ::: "memory");
        }
        barfence();
        mmac(0, af0, 1, bf1);
        barfence();
    }

    float bvv[2][2];
#pragma unroll
    for (int nh = 0; nh < 2; ++nh)
#pragma unroll
        for (int r = 0; r < 2; ++r)
            bvv[nh][r] = be[ntile * 256 + nh * 128 + wn * 32 + r * 16 + (lane & 15)];

    if (PHASE == 1) {
        __syncthreads();   // K-loop LDS fully retired
        short* tl = smem + wave * 640;   // 16 rows x 40 pitch (16B-aligned rows)
        const int kst = wn & 1;
#pragma unroll
        for (int mh = 0; mh < 2; ++mh) {
            const int out_gm = (outbase >> 7) + 2 * mtile + mh;
#pragma unroll
            for (int s = 0; s < 4; ++s) {
                const int fl = wm * 4 + s;
#pragma unroll
                for (int nh = 0; nh < 2; ++nh) {
                    // 16x32 chunk (bias + exact gelu) -> wave-private LDS
#pragma unroll
                    for (int r = 0; r < 2; ++r)
#pragma unroll
                        for (int q = 0; q < 4; ++q) {
                            float v = acc[mh][s][nh][r][q] + bvv[nh][r];
                            float g = 0.5f * v * (1.0f + erff(v * 0.70710678118654752f));
                            tl[((lane >> 4) * 4 + q) * 40 + r * 16 + (lane & 15)] =
                                (short)f2bf(g);
                        }
                    // read fragment-ordered, 16B coalesced store to phase-2 A page
                    uint4 u = *(const uint4*)(tl + (lane & 15) * 40 + (lane >> 4) * 8);
                    int kc2 = ntile * 4 + nh * 2 + (wn >> 1);
                    *(uint4*)(Aout + ((size_t)out_gm * 64 + kc2) * 8192
                              + (size_t)(fl * 2 + kst) * 512 + lane * 8) = u;
                }
            }
        }
    } else {
#pragma unroll
        for (int mh = 0; mh < 2; ++mh) {
            const int prow0 = outbase + mtile * 256 + mh * 128 + wm * 64;
#pragma unroll
            for (int s = 0; s < 4; ++s)
#pragma unroll
                for (int q = 0; q < 4; ++q) {
                    int p = prow0 + s * 16 + (lane >> 4) * 4 + q;
                    float* br = buf + (size_t)p * D_MODEL + ntile * 256;
#pragma unroll
                    for (int nh = 0; nh < 2; ++nh)
#pragma unroll
                        for (int r = 0; r < 2; ++r)
                            br[nh * 128 + wn * 32 + r * 16 + (lane & 15)] =
                                acc[mh][s][nh][r][q] + bvv[nh][r];
                }
        }
    }
}

// ---------------- final reduce: out[t] = sum_j pw[pj] * buf[pj] --------
__global__ __launch_bounds__(256) void reduce_kernel(
        const float* __restrict__ buf, const int* __restrict__ tpair,
        const float* __restrict__ pw, float* __restrict__ out) {
    int t = blockIdx.x;
    int c = threadIdx.x * 4;
    int p0 = tpair[4 * t], p1 = tpair[4 * t + 1];
    int p2 = tpair[4 * t + 2], p3 = tpair[4 * t + 3];
    float w0 = pw[p0], w1 = pw[p1], w2 = pw[p2], w3 = pw[p3];
    float4 a = *(const float4*)(buf + (size_t)p0 * D_MODEL + c);
    float4 b = *(const float4*)(buf + (size_t)p1 * D_MODEL + c);
    float4 d = *(const float4*)(buf + (size_t)p2 * D_MODEL + c);
    float4 e = *(const float4*)(buf + (size_t)p3 * D_MODEL + c);
    float4 o;
    o.x = w0 * a.x + w1 * b.x + w2 * d.x + w3 * e.x;
    o.y = w0 * a.y + w1 * b.y + w2 * d.y + w3 * e.y;
    o.z = w0 * a.z + w1 * b.z + w2 * d.z + w3 * e.z;
    o.w = w0 * a.w + w1 * b.w + w2 * d.w + w3 * e.w;
    *(float4*)(out + (size_t)t * D_MODEL + c) = o;
}

extern "C" void kernel_launch(void* const* d_in, const int* in_sizes, int n_in,
                              void* d_out, int out_size, void* d_ws, size_t ws_size,
                              hipStream_t stream) {
    const float* x   = (const float*)d_in[0];
    const float* rW  = (const float*)d_in[1];
    const float* rb  = (const float*)d_in[2];
    const float* W1  = (const float*)d_in[3];
    const float* b1  = (const float*)d_in[4];
    const float* W2  = (const float*)d_in[5];
    const float* b2  = (const float*)d_in[6];
    const float* sW1 = (const float*)d_in[7];
    const float* sb1 = (const float*)d_in[8];
    const float* sW2 = (const float*)d_in[9];
    const float* sb2 = (const float*)d_in[10];
    float* out = (float*)d_out;

    const int T = in_sizes[0] / D_MODEL;     // 4096
    const int MAXROWS = 18432;               // padded pair-row capacity (144 gm128)

    static int attr_done = 0;
    if (!attr_done) {
        hipFuncSetAttribute((const void*)moe_gemm<16, 16, 1>,
                            hipFuncAttributeMaxDynamicSharedMemorySize, 131072);
        hipFuncSetAttribute((const void*)moe_gemm<64, 4, 2>,
                            hipFuncAttributeMaxDynamicSharedMemorySize, 131072);
        attr_done = 1;
    }

    char* ws = (char*)d_ws;
    size_t o = 0;
    auto alloc = [&](size_t bytes) -> void* {
        void* p = ws + o;
        o += (bytes + 255) & ~(size_t)255;
        return p;
    };
    unsigned short* Wp1  = (unsigned short*)alloc((size_t)NVEXP * 16 * 16 * 16384 * 2);
    unsigned short* Wp2  = (unsigned short*)alloc((size_t)NVEXP * 4 * 64 * 16384 * 2);
    unsigned short* Ap1  = (unsigned short*)alloc((size_t)(MAXROWS / 128) * 16 * 8192 * 2);
    unsigned short* Ap2  = (unsigned short*)alloc((size_t)(MAXROWS / 128) * 64 * 8192 * 2);
    int*   ptok  = (int*)alloc((size_t)MAXROWS * 4);
    float* pwb   = (float*)alloc((size_t)MAXROWS * 4);
    int*   te    = (int*)alloc((size_t)T * 2 * 4);
    float* tw    = (float*)alloc((size_t)T * 2 * 4);
    int*   tpair = (int*)alloc((size_t)T * 4 * 4);
    int*   cnt   = (int*)alloc(64);
    int*   offs  = (int*)alloc(64);
    int*   cnt2  = (int*)alloc(64);
    int*   tmap  = (int*)alloc(512);
    // buf aliases Wp1 (phase 1 finished reading Wp1 before phase 2 writes buf):
    // needs 18432*1024*4 = 75.5 MB <= Wp1's 83.9 MB
    float* buf = (float*)Wp1;
    (void)ws_size; (void)n_in;

    hipMemsetAsync(cnt, 0, 64, stream);

    router_kernel<<<T / 4, 256, 0, stream>>>(x, rW, rb, te, tw, cnt);
    scan_kernel<<<1, 64, 0, stream>>>(cnt, offs, cnt2, tmap);
    scatter_kernel<<<T / 256, 256, 0, stream>>>(te, tw, offs, cnt2, ptok, pwb, tpair);

    apack_kernel<<<dim3(16, 32, 9), 256, 0, stream>>>(x, cnt, offs, ptok, Ap1);
    // both weight groups in one launch (group1: NT=16 NKC=16, group2: NT=4 NKC=64)
    wpack_all<<<20480, 256, 0, stream>>>(W1, sW1, W2, sW2, Wp1, Wp2);

    moe_gemm<16, 16, 1><<<dim3(72, 16, 1), 512, 131072, stream>>>(
        Wp1, Ap1, b1, sb1, tmap, offs, Ap2, nullptr);
    moe_gemm<64, 4, 2><<<dim3(72, 4, 1), 512, 131072, stream>>>(
        Wp2, Ap2, b2, sb2, tmap, offs, nullptr, buf);

    reduce_kernel<<<T, 256, 0, stream>>>(buf, tpair, pwb, out);
}

// Round 5
// 943.727 us; speedup vs baseline: 1.0457x; 1.0457x over previous
//
#include <hip/hip_runtime.h>
#include <math.h>

#define D_MODEL 1024
#define HIDDEN  4096
#define NEXP    8
#define NVEXP   10   // 8 routed + 2 shared

typedef __attribute__((ext_vector_type(8))) short short8;
typedef __attribute__((ext_vector_type(4))) float floatx4;

__device__ __forceinline__ unsigned short f2bf(float f) {
    unsigned int u = __float_as_uint(f);
    unsigned int r = (u + 0x7fffu + ((u >> 16) & 1u)) >> 16;
    return (unsigned short)r;
}

__device__ __forceinline__ void gll16(const void* g, void* l) {
    __builtin_amdgcn_global_load_lds(
        (const __attribute__((address_space(1))) unsigned int*)g,
        (__attribute__((address_space(3))) unsigned int*)l, 16, 0, 0);
}

// ---------------- router: wave per token, fp32 gates -------------------
__global__ __launch_bounds__(256) void router_kernel(
        const float* __restrict__ x, const float* __restrict__ rW,
        const float* __restrict__ rb, int* __restrict__ te, float* __restrict__ tw,
        int* __restrict__ cnt) {
    __shared__ float rws[8 * 1024];   // rws[e][d]
    int tid = threadIdx.x;
    for (int i = tid; i < 8192; i += 256) {
        int dd = i >> 3, e = i & 7;
        rws[e * 1024 + dd] = rW[i];
    }
    __syncthreads();
    int tok = blockIdx.x * 4 + (tid >> 6);
    int lane = tid & 63;
    const float* xr = x + (size_t)tok * D_MODEL;
    float acc[8];
#pragma unroll
    for (int e = 0; e < 8; ++e) acc[e] = 0.f;
    for (int k = 0; k < 16; ++k) {
        int dd = k * 64 + lane;
        float xv = xr[dd];
#pragma unroll
        for (int e = 0; e < 8; ++e) acc[e] += xv * rws[e * 1024 + dd];
    }
#pragma unroll
    for (int m = 1; m < 64; m <<= 1) {
#pragma unroll
        for (int e = 0; e < 8; ++e) acc[e] += __shfl_xor(acc[e], m);
    }
    if (lane == 0) {
        float g[8];
#pragma unroll
        for (int e = 0; e < 8; ++e) g[e] = acc[e] + rb[e];
        int i0 = 0; float v0 = g[0];
#pragma unroll
        for (int e = 1; e < 8; ++e) if (g[e] > v0) { v0 = g[e]; i0 = e; }
        int i1 = -1; float v1 = -1e30f;
#pragma unroll
        for (int e = 0; e < 8; ++e) if (e != i0 && g[e] > v1) { v1 = g[e]; i1 = e; }
        float ex = expf(v1 - v0);
        float p0 = 1.0f / (1.0f + ex);
        float p1 = 1.0f - p0;
        te[tok * 2] = i0; te[tok * 2 + 1] = i1;
        tw[tok * 2] = p0; tw[tok * 2 + 1] = p1;
        atomicAdd(cnt + i0, 1);
        atomicAdd(cnt + i1, 1);
    }
}

// offs[e] padded to multiples of 128; offs[8] = shared-A base (also z=8 out),
// offs[9] = z=9 out base. tmap: [0]=ntiles, [1+i] = z | (mtile<<8) for each
// active 128-row tile (dense, ordered).
__global__ void scan_kernel(const int* __restrict__ cnt, int* __restrict__ offs,
                            int* __restrict__ cnt2, int* __restrict__ tmap) {
    if (threadIdx.x == 0) {
        int o = 0;
        for (int e = 0; e < 8; ++e) { offs[e] = o; o += (cnt[e] + 127) & ~127; }
        offs[8] = o; offs[9] = o + 4096;
        int nt = 0;
        for (int e = 0; e < NVEXP; ++e) {
            int c = (e < 8) ? cnt[e] : 4096;
            for (int m = 0; m * 128 < c; ++m) tmap[1 + nt++] = e | (m << 8);
        }
        tmap[0] = nt;   // <= 135
    }
    if (threadIdx.x < 8) cnt2[threadIdx.x] = 0;
}

__global__ __launch_bounds__(256) void scatter_kernel(
        const int* __restrict__ te, const float* __restrict__ tw,
        const int* __restrict__ offs, int* __restrict__ cnt2,
        int* __restrict__ ptok, float* __restrict__ pw, int* __restrict__ tpair) {
    int t = blockIdx.x * 256 + threadIdx.x;
    int e0 = te[2 * t], e1 = te[2 * t + 1];
    int s0 = atomicAdd(cnt2 + e0, 1);
    int pos0 = offs[e0] + s0;
    ptok[pos0] = t; pw[pos0] = tw[2 * t];
    int s1 = atomicAdd(cnt2 + e1, 1);
    int pos1 = offs[e1] + s1;
    ptok[pos1] = t; pw[pos1] = tw[2 * t + 1];
    int b8 = offs[8], b9 = offs[9];
    ptok[b8 + t] = t; pw[b8 + t] = 0.5f;
    ptok[b9 + t] = t; pw[b9 + t] = 0.5f;
    tpair[4 * t + 0] = pos0; tpair[4 * t + 1] = pos1;
    tpair[4 * t + 2] = b8 + t; tpair[4 * t + 3] = b9 + t;
}

// ------- weight pack (both groups, one launch) -------------------------
// src fp32 [R(k)][C(n)] -> [z][ntile(C/256)][kc(R/64)][frag16][kstep2][lane64][8]
__global__ __launch_bounds__(256) void wpack_all(
        const float* __restrict__ W1, const float* __restrict__ sW1,
        const float* __restrict__ W2, const float* __restrict__ sW2,
        unsigned short* __restrict__ Wp1, unsigned short* __restrict__ Wp2) {
    int bid = blockIdx.x;
    const float* src; unsigned short* dst;
    int R, C, cx, ry, z;
    if (bid < 10240) {            // group 1: R=1024, C=4096 (64 c-tiles, 16 r-tiles)
        z = bid >> 10; int rem = bid & 1023;
        cx = rem & 63; ry = rem >> 6;
        R = 1024; C = 4096;
        src = (z < NEXP) ? W1 + (size_t)z * R * C : sW1 + (size_t)(z - NEXP) * R * C;
        dst = Wp1;
    } else {                      // group 2: R=4096, C=1024 (16 c-tiles, 64 r-tiles)
        bid -= 10240;
        z = bid >> 10; int rem = bid & 1023;
        cx = rem & 15; ry = rem >> 4;
        R = 4096; C = 1024;
        src = (z < NEXP) ? W2 + (size_t)z * R * C : sW2 + (size_t)(z - NEXP) * R * C;
        dst = Wp2;
    }
    int c0 = cx * 64, r0 = ry * 64;
    __shared__ float tile[64][65];
    int t = threadIdx.x;
    int rl = t >> 4, cl = (t & 15) * 4;
#pragma unroll
    for (int p = 0; p < 4; ++p) {
        int r = p * 16 + rl;
        const float4 v = *(const float4*)&src[(size_t)(r0 + r) * C + c0 + cl];
        tile[r][cl] = v.x; tile[r][cl + 1] = v.y; tile[r][cl + 2] = v.z; tile[r][cl + 3] = v.w;
    }
    __syncthreads();
    int NT = C >> 8, NKC = R >> 6;
    int ntile = c0 >> 8, f0 = (c0 >> 4) & 15, kc = ry;
    unsigned short* base = dst + ((size_t)(z * NT + ntile) * NKC + kc) * 16384;
#pragma unroll
    for (int w = 0; w < 2; ++w) {
        int si = w * 256 + t;            // 0..511
        int fl = si >> 7, rem = si & 127;
        int kst = rem >> 6, l2 = rem & 63;
        int n_l = fl * 16 + (l2 & 15);
        int k_l = kst * 32 + (l2 >> 4) * 8;
        unsigned int u[4];
#pragma unroll
        for (int i = 0; i < 4; ++i) {
            unsigned short lo = f2bf(tile[k_l + 2 * i][n_l]);
            unsigned short hi = f2bf(tile[k_l + 2 * i + 1][n_l]);
            u[i] = lo | ((unsigned)hi << 16);
        }
        *(uint4*)(base + ((size_t)(f0 + fl) * 2 + kst) * 512 + (size_t)l2 * 8) =
            make_uint4(u[0], u[1], u[2], u[3]);
    }
}

// ------- A pack (phase 1): gather x rows by ptok, cast, fragment-pack --
// dst layout: [gm128][kc16][frag8][kstep2][lane64][8]  (16KB pages)
__global__ __launch_bounds__(256) void apack_kernel(
        const float* __restrict__ x, const int* __restrict__ counts,
        const int* __restrict__ offs, const int* __restrict__ ptok,
        unsigned short* __restrict__ dst) {
    int z = blockIdx.z;               // 0..8 (8 = shared section, written once)
    int cnt = (z < NEXP) ? counts[z] : 4096;
    int pbase = offs[z];
    int mtile = blockIdx.y;
    if (mtile * 128 >= cnt) return;
    int kc = blockIdx.x;
    int gm = (pbase >> 7) + mtile;
    unsigned short* d = dst + ((size_t)gm * 16 + kc) * 8192;
    int t = threadIdx.x;
#pragma unroll
    for (int w = 0; w < 4; ++w) {
        int si = w * 256 + t;            // 0..1023
        int fl = si >> 7, rem = si & 127;
        int kst = rem >> 6, l2 = rem & 63;
        int row = fl * 16 + (l2 & 15);
        int k0 = kc * 64 + kst * 32 + (l2 >> 4) * 8;
        int idx = mtile * 128 + row;
        if (idx >= cnt) idx = cnt - 1;
        int tok = ptok[pbase + idx];
        const float4* p = (const float4*)(x + (size_t)tok * D_MODEL + k0);
        float4 a = p[0], b = p[1];
        unsigned int u0 = f2bf(a.x) | ((unsigned)f2bf(a.y) << 16);
        unsigned int u1 = f2bf(a.z) | ((unsigned)f2bf(a.w) << 16);
        unsigned int u2 = f2bf(b.x) | ((unsigned)f2bf(b.y) << 16);
        unsigned int u3 = f2bf(b.z) | ((unsigned)f2bf(b.w) << 16);
        *(uint4*)(d + (size_t)si * 8) = make_uint4(u0, u1, u2, u3);
    }
}

// -------- grouped MFMA GEMM, m97 structure: BM=128, BN=128, BK=64 ------
// 4 waves (2x2), wave tile 64x64, acc[4][4]. 32KB single-buffer LDS ->
// 3 blocks/CU resident; inter-block overlap hides staging (m97 mechanism).
// Simple 2-barrier K-loop, compiler-scheduled waits. Grid: x = dense tile
// slot (tmap), y = ntile128; x fastest -> consecutive blocks share B panel.
template <int NKC, int NTW, int PHASE>
__global__ __launch_bounds__(256, 3) void moe_gemm(
        const unsigned short* __restrict__ Wp,
        const unsigned short* __restrict__ Ap,
        const float* __restrict__ bias, const float* __restrict__ sbias,
        const int* __restrict__ tmap, const int* __restrict__ offs,
        unsigned short* __restrict__ Aout, float* __restrict__ buf) {
    __shared__ __align__(16) short smem[16384];   // As 16KB + Bs 16KB
    short* As = smem;
    short* Bs = smem + 8192;

    const int tile = blockIdx.x;
    if (tile >= tmap[0]) return;
    const int tv = tmap[1 + tile];
    const int z = tv & 255;
    const int mtile = tv >> 8;
    const int ntile = blockIdx.y;              // 0 .. 2*NTW-1 (128-wide)

    const int outbase = offs[z];
    const int inbase = (PHASE == 1 && z >= NEXP) ? offs[8] : outbase;
    const int tid = threadIdx.x;
    const int wave = tid >> 6, lane = tid & 63;
    const int wm = wave >> 1, wn = wave & 1;   // 2 x 2
    const int gm = (inbase >> 7) + mtile;
    const int NDIM = NTW * 256;

    const unsigned short* Apg = Ap + (size_t)gm * NKC * 8192;
    const unsigned short* Bpg = Wp + ((size_t)(z * NTW + (ntile >> 1)) * NKC) * 16384
                                   + (size_t)(ntile & 1) * 8192;
    const float* be = (z < NEXP) ? bias + (size_t)z * NDIM
                                 : sbias + (size_t)(z - NEXP) * NDIM;

    floatx4 acc[4][4];
#pragma unroll
    for (int s = 0; s < 4; ++s)
#pragma unroll
        for (int r = 0; r < 4; ++r) acc[s][r] = (floatx4){0.f, 0.f, 0.f, 0.f};

    for (int kc = 0; kc < NKC; ++kc) {
        __syncthreads();
        const unsigned short* ga = Apg + (size_t)kc * 8192 + tid * 8;
        const unsigned short* gb = Bpg + (size_t)kc * 16384 + tid * 8;
        short* la = As + tid * 8;
        short* lb = Bs + tid * 8;
#pragma unroll
        for (int q = 0; q < 4; ++q) gll16(ga + q * 2048, la + q * 2048);
#pragma unroll
        for (int q = 0; q < 4; ++q) gll16(gb + q * 2048, lb + q * 2048);
        __syncthreads();
#pragma unroll
        for (int ks = 0; ks < 2; ++ks) {
            short8 af[4], bfr[4];
#pragma unroll
            for (int s = 0; s < 4; ++s)
                af[s] = *(const short8*)(As + ((wm * 4 + s) * 2 + ks) * 512 + lane * 8);
#pragma unroll
            for (int r = 0; r < 4; ++r)
                bfr[r] = *(const short8*)(Bs + ((wn * 4 + r) * 2 + ks) * 512 + lane * 8);
#pragma unroll
            for (int s = 0; s < 4; ++s)
#pragma unroll
                for (int r = 0; r < 4; ++r)
                    acc[s][r] = __builtin_amdgcn_mfma_f32_16x16x32_bf16(af[s], bfr[r], acc[s][r], 0, 0, 0);
        }
    }

    float bv[4];
#pragma unroll
    for (int r = 0; r < 4; ++r)
        bv[r] = be[ntile * 128 + wn * 64 + r * 16 + (lane & 15)];

    if (PHASE == 1) {
        __syncthreads();   // K-loop LDS fully retired
        short* tl = smem + wave * 1152;   // 16 rows x 72 pitch (16B-aligned rows)
        const int out_gm = (outbase >> 7) + mtile;
        const int kc2 = ntile * 2 + wn;
#pragma unroll
        for (int s = 0; s < 4; ++s) {
            const int fl = wm * 4 + s;
            // 16x64 chunk (bias + exact gelu) -> wave-private LDS
#pragma unroll
            for (int r = 0; r < 4; ++r)
#pragma unroll
                for (int q = 0; q < 4; ++q) {
                    float v = acc[s][r][q] + bv[r];
                    float g = 0.5f * v * (1.0f + erff(v * 0.70710678118654752f));
                    tl[((lane >> 4) * 4 + q) * 72 + r * 16 + (lane & 15)] = (short)f2bf(g);
                }
            // read fragment-ordered, 16B coalesced store to phase-2 A page
#pragma unroll
            for (int kst = 0; kst < 2; ++kst) {
                uint4 u = *(const uint4*)(tl + (lane & 15) * 72 + kst * 32 + (lane >> 4) * 8);
                *(uint4*)(Aout + ((size_t)out_gm * 64 + kc2) * 8192
                          + (size_t)(fl * 2 + kst) * 512 + lane * 8) = u;
            }
        }
    } else {
        const int prow0 = outbase + mtile * 128 + wm * 64;
#pragma unroll
        for (int s = 0; s < 4; ++s)
#pragma unroll
            for (int q = 0; q < 4; ++q) {
                int p = prow0 + s * 16 + (lane >> 4) * 4 + q;
                float* br = buf + (size_t)p * D_MODEL + ntile * 128 + wn * 64;
#pragma unroll
                for (int r = 0; r < 4; ++r)
                    br[r * 16 + (lane & 15)] = acc[s][r][q] + bv[r];
            }
    }
}

// ---------------- final reduce: out[t] = sum_j pw[pj] * buf[pj] --------
__global__ __launch_bounds__(256) void reduce_kernel(
        const float* __restrict__ buf, const int* __restrict__ tpair,
        const float* __restrict__ pw, float* __restrict__ out) {
    int t = blockIdx.x;
    int c = threadIdx.x * 4;
    int p0 = tpair[4 * t], p1 = tpair[4 * t + 1];
    int p2 = tpair[4 * t + 2], p3 = tpair[4 * t + 3];
    float w0 = pw[p0], w1 = pw[p1], w2 = pw[p2], w3 = pw[p3];
    float4 a = *(const float4*)(buf + (size_t)p0 * D_MODEL + c);
    float4 b = *(const float4*)(buf + (size_t)p1 * D_MODEL + c);
    float4 d = *(const float4*)(buf + (size_t)p2 * D_MODEL + c);
    float4 e = *(const float4*)(buf + (size_t)p3 * D_MODEL + c);
    float4 o;
    o.x = w0 * a.x + w1 * b.x + w2 * d.x + w3 * e.x;
    o.y = w0 * a.y + w1 * b.y + w2 * d.y + w3 * e.y;
    o.z = w0 * a.z + w1 * b.z + w2 * d.z + w3 * e.z;
    o.w = w0 * a.w + w1 * b.w + w2 * d.w + w3 * e.w;
    *(float4*)(out + (size_t)t * D_MODEL + c) = o;
}

extern "C" void kernel_launch(void* const* d_in, const int* in_sizes, int n_in,
                              void* d_out, int out_size, void* d_ws, size_t ws_size,
                              hipStream_t stream) {
    const float* x   = (const float*)d_in[0];
    const float* rW  = (const float*)d_in[1];
    const float* rb  = (const float*)d_in[2];
    const float* W1  = (const float*)d_in[3];
    const float* b1  = (const float*)d_in[4];
    const float* W2  = (const float*)d_in[5];
    const float* b2  = (const float*)d_in[6];
    const float* sW1 = (const float*)d_in[7];
    const float* sb1 = (const float*)d_in[8];
    const float* sW2 = (const float*)d_in[9];
    const float* sb2 = (const float*)d_in[10];
    float* out = (float*)d_out;

    const int T = in_sizes[0] / D_MODEL;     // 4096
    const int MAXROWS = 18432;               // padded pair-row capacity

    char* ws = (char*)d_ws;
    size_t o = 0;
    auto alloc = [&](size_t bytes) -> void* {
        void* p = ws + o;
        o += (bytes + 255) & ~(size_t)255;
        return p;
    };
    unsigned short* Wp1  = (unsigned short*)alloc((size_t)NVEXP * 16 * 16 * 16384 * 2);
    unsigned short* Wp2  = (unsigned short*)alloc((size_t)NVEXP * 4 * 64 * 16384 * 2);
    unsigned short* Ap1  = (unsigned short*)alloc((size_t)(MAXROWS / 128) * 16 * 8192 * 2);
    unsigned short* Ap2  = (unsigned short*)alloc((size_t)(MAXROWS / 128) * 64 * 8192 * 2);
    int*   ptok  = (int*)alloc((size_t)MAXROWS * 4);
    float* pwb   = (float*)alloc((size_t)MAXROWS * 4);
    int*   te    = (int*)alloc((size_t)T * 2 * 4);
    float* tw    = (float*)alloc((size_t)T * 2 * 4);
    int*   tpair = (int*)alloc((size_t)T * 4 * 4);
    int*   cnt   = (int*)alloc(64);
    int*   offs  = (int*)alloc(64);
    int*   cnt2  = (int*)alloc(64);
    int*   tmap  = (int*)alloc(1024);
    // buf aliases Wp1 (phase 1 finished reading Wp1 before phase 2 writes buf):
    // needs 18432*1024*4 = 75.5 MB <= Wp1's 83.9 MB
    float* buf = (float*)Wp1;
    (void)ws_size; (void)n_in;

    hipMemsetAsync(cnt, 0, 64, stream);

    router_kernel<<<T / 4, 256, 0, stream>>>(x, rW, rb, te, tw, cnt);
    scan_kernel<<<1, 64, 0, stream>>>(cnt, offs, cnt2, tmap);
    scatter_kernel<<<T / 256, 256, 0, stream>>>(te, tw, offs, cnt2, ptok, pwb, tpair);

    apack_kernel<<<dim3(16, 32, 9), 256, 0, stream>>>(x, cnt, offs, ptok, Ap1);
    // both weight groups in one launch (group1: NT=16 NKC=16, group2: NT=4 NKC=64)
    wpack_all<<<20480, 256, 0, stream>>>(W1, sW1, W2, sW2, Wp1, Wp2);

    // phase 1: K=1024 (NKC=16), N=4096 (32 n-tiles of 128)
    moe_gemm<16, 16, 1><<<dim3(144, 32), 256, 0, stream>>>(
        Wp1, Ap1, b1, sb1, tmap, offs, Ap2, nullptr);
    // phase 2: K=4096 (NKC=64), N=1024 (8 n-tiles of 128)
    moe_gemm<64, 4, 2><<<dim3(144, 8), 256, 0, stream>>>(
        Wp2, Ap2, b2, sb2, tmap, offs, nullptr, buf);

    reduce_kernel<<<T, 256, 0, stream>>>(buf, tpair, pwb, out);
}